// Round 2
// baseline (128.404 us; speedup 1.0000x reference)
//
#include <hip/hip_runtime.h>

// make_blocks: out[b,p,a,c,:] = concat(seq1M[b, r0+c, :], seq2M[b, c0+a, :], geo[b,p,a,c])
// Shapes: B=64, L=2048, D=60, P=16, PS=30, out [B,P,PS,PS,2D+1] fp32.
//
// Wave-per-(a,c)-pair scheme: each 121-float output row is written by one wave,
// lane index == k. No div/mod per element, uniform control flow, unit-stride LDS.

constexpr int B_    = 64;
constexpr int L_    = 2048;
constexpr int D_    = 60;
constexpr int P_    = 16;
constexpr int PS_   = 30;
constexpr int KOUT  = 2 * D_ + 1;        // 121
constexpr int NPAIR = PS_ * PS_;         // 900 (a,c) pairs per (b,p)
constexpr int CHUNK = NPAIR * KOUT;      // 108900 floats per (b,p)
constexpr int SPLIT = 2;                 // blocks per (b,p) -> 8 waves per chunk
constexpr int NT    = 256;
constexpr int WAVES_PER_CHUNK = SPLIT * (NT / 64);  // 8

__global__ __launch_bounds__(NT) void make_blocks_38860864094557_kernel(
    const float* __restrict__ seq1, const float* __restrict__ seq2,
    const float* __restrict__ geo,  const int* __restrict__ patches,
    float* __restrict__ out)
{
    __shared__ float sh_rows[PS_ * D_];   // rows[c][d] = seq1M[b, r0+c, d]
    __shared__ float sh_cols[PS_ * D_];   // cols[a][d] = seq2M[b, c0+a, d]
    __shared__ float sh_geo [NPAIR];      // geo[a][c] == geo[q]

    const int bid = blockIdx.x;
    const int bp  = bid / SPLIT;          // which (b,p)
    const int s   = bid % SPLIT;
    const int b   = bp / P_;

    const int r0 = patches[bp * 2 + 0];
    const int c0 = patches[bp * 2 + 1];

    // Contiguous, 16B-aligned source spans (D=60, PS*PS=900 are %4==0).
    const float4* rsrc = reinterpret_cast<const float4*>(seq1 + ((size_t)b * L_ + r0) * D_);
    const float4* csrc = reinterpret_cast<const float4*>(seq2 + ((size_t)b * L_ + c0) * D_);
    const float4* gsrc = reinterpret_cast<const float4*>(geo  + (size_t)bp * NPAIR);

    for (int i = threadIdx.x; i < PS_ * D_ / 4; i += NT) {   // 450 float4 each
        reinterpret_cast<float4*>(sh_rows)[i] = rsrc[i];
        reinterpret_cast<float4*>(sh_cols)[i] = csrc[i];
    }
    for (int i = threadIdx.x; i < NPAIR / 4; i += NT) {      // 225 float4
        reinterpret_cast<float4*>(sh_geo)[i] = gsrc[i];
    }
    __syncthreads();

    const int lane = threadIdx.x & 63;
    const int wid  = threadIdx.x >> 6;
    const int gw   = s * (NT / 64) + wid;                    // 0..7 within chunk

    float* chunk = out + (size_t)bp * CHUNK;

    // Each wave: one (a,c) pair per iteration; lane == k.
    for (int q = gw; q < NPAIR; q += WAVES_PER_CHUNK) {
        const int a = q / PS_;            // wave-uniform; magic-mul
        const int c = q - a * PS_;
        float* dst = chunk + q * KOUT;

        // k = 0..59 : rows[c][:]
        if (lane < D_) dst[lane] = sh_rows[c * D_ + lane];

        // k = 60..119 : cols[a][:], k = 120 : geo[q]  (lane 60 carries geo)
        const float v = (lane < D_) ? sh_cols[a * D_ + lane] : sh_geo[q];
        if (lane < D_ + 1) dst[D_ + lane] = v;
    }
}

extern "C" void kernel_launch(void* const* d_in, const int* in_sizes, int n_in,
                              void* d_out, int out_size, void* d_ws, size_t ws_size,
                              hipStream_t stream) {
    const float* seq1    = (const float*)d_in[0];
    const float* seq2    = (const float*)d_in[1];
    const float* geo     = (const float*)d_in[2];
    const int*   patches = (const int*)d_in[3];
    float*       out     = (float*)d_out;

    const int grid = B_ * P_ * SPLIT;     // 2048 blocks, 8/CU
    make_blocks_38860864094557_kernel<<<grid, NT, 0, stream>>>(seq1, seq2, geo, patches, out);
}

// Round 3
// 113.002 us; speedup vs baseline: 1.1363x; 1.1363x over previous
//
#include <hip/hip_runtime.h>

// make_blocks: out[b,p,a,c,:] = concat(seq1M[b, r0+c, :], seq2M[b, c0+a, :], geo[b,p,a,c])
// B=64, L=2048, D=60, P=16, PS=30 -> out [64,16,30,30,121] fp32 (446 MB).
//
// Descriptor scheme: the per-(b,p) chunk is 30 'a'-rows x 3630 floats. An a-PAIR
// stripe (7260 floats = 1815 float4) is 16B-aligned and its gather pattern is
// identical across stripes up to a per-component constant LDS stride:
//   rows part (k<60):   sh_rows[c*61+k]            stride 0   per stripe
//   cols part (60..119):sh_cols[(a&1)*61 + k-60]   stride 122 floats per stripe
//   geo  part (k==120): sh_geo [(a&1)*30 + c]      stride 60  floats per stripe
// Each thread precomputes 4 byte-(offset,stride) pairs per owned float4 ONCE;
// the hot loop is 4x(ds_read_b32 + v_add) + one dwordx4 store per float4.

constexpr int B_    = 64;
constexpr int L_    = 2048;
constexpr int D_    = 60;
constexpr int P_    = 16;
constexpr int PS_   = 30;
constexpr int KOUT  = 2 * D_ + 1;          // 121
constexpr int NPAIR = PS_ * PS_;           // 900
constexpr int CHUNK = NPAIR * KOUT;        // 108900 floats per (b,p)
constexpr int AP_FLOATS = 2 * PS_ * KOUT;  // 7260 floats per a-pair stripe
constexpr int AP_F4     = AP_FLOATS / 4;   // 1815
constexpr int NAP       = PS_ / 2;         // 15 stripes per chunk

constexpr int NT = 512;
constexpr int NS = (AP_F4 + NT - 1) / NT;  // 4 float4 slots per thread

constexpr int RPAD = 61;                   // padded row stride (floats)
constexpr int CB   = PS_ * RPAD;           // cols base: 1830
constexpr int GB   = CB + PS_ * RPAD;      // geo base:  3660
constexpr int LDSF = GB + NPAIR;           // 4560 floats = 18.24 KB

__global__ __launch_bounds__(NT) void make_blocks_38860864094557_kernel(
    const float* __restrict__ seq1, const float* __restrict__ seq2,
    const float* __restrict__ geo,  const int* __restrict__ patches,
    float* __restrict__ out)
{
    __shared__ float sh[LDSF];

    const int bp = blockIdx.x;        // (b,p)
    const int b  = bp / P_;
    const int tid = threadIdx.x;

    const int r0 = patches[bp * 2 + 0];
    const int c0 = patches[bp * 2 + 1];

    const float* s1 = seq1 + ((size_t)b * L_ + r0) * D_;   // 1800 contiguous floats
    const float* s2 = seq2 + ((size_t)b * L_ + c0) * D_;
    const float* gg = geo  + (size_t)bp * NPAIR;

    // Stage rows & cols (padded to stride 61) and geo.
    for (int i = tid; i < PS_ * RPAD; i += NT) {
        const int c  = i / RPAD;           // compile-time magic div
        const int kk = i - c * RPAD;
        if (kk < D_) {
            sh[i]      = s1[c * D_ + kk];
            sh[CB + i] = s2[c * D_ + kk];
        }
    }
    for (int i = tid; i < NPAIR; i += NT) sh[GB + i] = gg[i];
    __syncthreads();

    // Precompute per-thread descriptors (byte offsets + per-stripe byte strides).
    int offb[NS][4];
    int strb[NS][4];
    bool valid[NS];
#pragma unroll
    for (int s = 0; s < NS; ++s) {
        const int u4 = tid + s * NT;
        valid[s] = (u4 < AP_F4);
        const int u4c = valid[s] ? u4 : (AP_F4 - 1);
#pragma unroll
        for (int j = 0; j < 4; ++j) {
            const int u  = 4 * u4c + j;          // float index within stripe [0,7260)
            const int ah = (u >= PS_ * KOUT) ? 1 : 0;
            const int r  = u - ah * PS_ * KOUT;  // [0,3630)
            const int c  = r / KOUT;             // magic div
            const int k  = r - c * KOUT;
            int off, st;
            if (k < D_)            { off = c * RPAD + k;               st = 0; }
            else if (k < 2 * D_)   { off = CB + ah * RPAD + (k - D_);  st = 2 * RPAD; }
            else                   { off = GB + ah * PS_ + c;          st = 2 * PS_; }
            offb[s][j] = off * 4;
            strb[s][j] = st * 4;
        }
    }

    float4* outf4 = reinterpret_cast<float4*>(out + (size_t)bp * CHUNK);
    const char* shb = reinterpret_cast<const char*>(sh);

    // 15 a-pair stripes: per thread per stripe, up to NS float4s, each
    // 4x(ds_read_b32 + add) + one contiguous dwordx4 store.
    for (int ap = 0; ap < NAP; ++ap) {
#pragma unroll
        for (int s = 0; s < NS; ++s) {
            if (valid[s]) {
                float4 v;
                v.x = *reinterpret_cast<const float*>(shb + offb[s][0]);
                v.y = *reinterpret_cast<const float*>(shb + offb[s][1]);
                v.z = *reinterpret_cast<const float*>(shb + offb[s][2]);
                v.w = *reinterpret_cast<const float*>(shb + offb[s][3]);
                outf4[ap * AP_F4 + tid + s * NT] = v;
            }
#pragma unroll
            for (int j = 0; j < 4; ++j) offb[s][j] += strb[s][j];
        }
    }
}

extern "C" void kernel_launch(void* const* d_in, const int* in_sizes, int n_in,
                              void* d_out, int out_size, void* d_ws, size_t ws_size,
                              hipStream_t stream) {
    const float* seq1    = (const float*)d_in[0];
    const float* seq2    = (const float*)d_in[1];
    const float* geo     = (const float*)d_in[2];
    const int*   patches = (const int*)d_in[3];
    float*       out     = (float*)d_out;

    const int grid = B_ * P_;   // 1024 blocks, one per (b,p); 4 blocks/CU, 32 waves/CU
    make_blocks_38860864094557_kernel<<<grid, NT, 0, stream>>>(seq1, seq2, geo, patches, out);
}